// Round 1
// baseline (1765.684 us; speedup 1.0000x reference)
//
#include <hip/hip_runtime.h>

#define N_NODES 100000
#define N_EDGES 1600000
#define NB 64
#define NI 64
#define EI 32
#define GI 32
#define NO 32
#define EO 32
#define GO 32
#define HH 3
#define HNO 96   /* H*NO */
#define NEG 0.2f

// ---------------- K0: xl = x@W_l + b_l, xr = x@W_r + b_r  [N,96] each ----------------
__global__ __launch_bounds__(256) void k0_node_transform(
    const float* __restrict__ x, const float* __restrict__ W_l, const float* __restrict__ b_l,
    const float* __restrict__ W_r, const float* __restrict__ b_r,
    float* __restrict__ xl, float* __restrict__ xr, int niters)
{
    __shared__ float sWl[NI * HNO];   // 24 KB
    __shared__ float sWr[NI * HNO];   // 24 KB
    __shared__ float sx[8][NI];       // 2 KB
    int t = threadIdx.x;
    for (int f = t; f < NI * HNO; f += 256) { sWl[f] = W_l[f]; sWr[f] = W_r[f]; }
    __syncthreads();
    int k = t & 31, ni = t >> 5;
    float bl0 = b_l[k], bl1 = b_l[k + 32], bl2 = b_l[k + 64];
    float br0 = b_r[k], br1 = b_r[k + 32], br2 = b_r[k + 64];
    for (int it = 0; it < niters; ++it) {
        long g = (long)blockIdx.x + (long)it * gridDim.x;
        long n = g * 8 + ni;
        long nc = (n < N_NODES) ? n : 0;
        sx[ni][k]      = x[nc * NI + k];
        sx[ni][k + 32] = x[nc * NI + k + 32];
        __syncthreads();
        float al0 = bl0, al1 = bl1, al2 = bl2;
        float ar0 = br0, ar1 = br1, ar2 = br2;
        #pragma unroll 8
        for (int i = 0; i < NI; ++i) {
            float xv = sx[ni][i];
            al0 += xv * sWl[i * HNO + k];
            al1 += xv * sWl[i * HNO + k + 32];
            al2 += xv * sWl[i * HNO + k + 64];
            ar0 += xv * sWr[i * HNO + k];
            ar1 += xv * sWr[i * HNO + k + 32];
            ar2 += xv * sWr[i * HNO + k + 64];
        }
        if (n < N_NODES) {
            xl[n * HNO + k]      = al0; xl[n * HNO + k + 32] = al1; xl[n * HNO + k + 64] = al2;
            xr[n * HNO + k]      = ar0; xr[n * HNO + k + 32] = ar1; xr[n * HNO + k + 64] = ar2;
        }
        __syncthreads();
    }
}

// ---------------- K1: fused edge pass ----------------
// e = relu([x[src], ea] @ W_edge + b_edge)           -> write d_out
// h = xl[src] + xr[dst] + e @ W_e
// logit_h = sum_k leakyrelu(h)*att ; ex = exp(logit)  (no max-subtraction: logits O(1))
// atomic: den[dst,h] += ex ;  gat[dst,h,k] += ex * xl[src,h,k]
__global__ __launch_bounds__(256) void k1_edge(
    const float* __restrict__ x, const float* __restrict__ ea,
    const float* __restrict__ W_edge, const float* __restrict__ b_edge,
    const float* __restrict__ W_e, const float* __restrict__ att,
    const int* __restrict__ eidx,   // [2, E]
    const float* __restrict__ xl, const float* __restrict__ xr,
    float* __restrict__ e_out, float* __restrict__ den, float* __restrict__ gat,
    int niters)
{
    __shared__ float sWedge[96 * 32];  // 12 KB  W_edge[i][k] = [i*32+k]
    __shared__ float sWe[32 * 96];     // 12 KB  W_e[i][j]    = [i*96+j]
    __shared__ float sAtt[96];
    __shared__ float sIn[8][96];       // 3 KB   concat(x[src], ea) per edge
    __shared__ float sEo[8][32];       // 1 KB
    int t = threadIdx.x;
    for (int f = t; f < 96 * 32; f += 256) { sWedge[f] = W_edge[f]; sWe[f] = W_e[f]; }
    if (t < 96) sAtt[t] = att[t];
    __syncthreads();
    int k = t & 31, eg = t >> 5;    // 8 edges per block-iteration
    float be = b_edge[k];
    for (int it = 0; it < niters; ++it) {
        long e0 = ((long)blockIdx.x + (long)it * gridDim.x) * 8;
        // --- P0: stage inputs: 8 edges x 96 features, 3 elements/thread ---
        #pragma unroll
        for (int r = 0; r < 3; ++r) {
            int f = r * 256 + t;          // 0..767
            int ei2 = f / 96;             // edge-in-group
            int i = f - ei2 * 96;
            long e = e0 + ei2;
            long ec = (e < N_EDGES) ? e : 0;
            int s = eidx[ec];
            float v = (i < NI) ? x[(long)s * NI + i] : ea[ec * EI + (i - NI)];
            sIn[ei2][i] = v;
        }
        __syncthreads();
        // --- P1: edge MLP (one output feature per thread) ---
        long e = e0 + eg;
        bool valid = (e < N_EDGES);
        long ec = valid ? e : 0;
        float acc = be;
        #pragma unroll 8
        for (int i = 0; i < 96; ++i) acc += sIn[eg][i] * sWedge[i * 32 + k];
        acc = fmaxf(acc, 0.f);
        sEo[eg][k] = acc;
        if (valid) e_out[ec * EO + k] = acc;
        __syncthreads();
        // --- P2: h, logits, exp, atomics ---
        int s = eidx[ec];
        int d = eidx[N_EDGES + ec];
        float xlv0 = xl[(long)s * HNO + k];
        float xlv1 = xl[(long)s * HNO + k + 32];
        float xlv2 = xl[(long)s * HNO + k + 64];
        float h0 = xlv0 + xr[(long)d * HNO + k];
        float h1 = xlv1 + xr[(long)d * HNO + k + 32];
        float h2 = xlv2 + xr[(long)d * HNO + k + 64];
        #pragma unroll 8
        for (int i = 0; i < 32; ++i) {
            float eo = sEo[eg][i];
            h0 += eo * sWe[i * 96 + k];
            h1 += eo * sWe[i * 96 + 32 + k];
            h2 += eo * sWe[i * 96 + 64 + k];
        }
        float p0 = (h0 > 0.f ? h0 : NEG * h0) * sAtt[k];
        float p1 = (h1 > 0.f ? h1 : NEG * h1) * sAtt[32 + k];
        float p2 = (h2 > 0.f ? h2 : NEG * h2) * sAtt[64 + k];
        #pragma unroll
        for (int m = 1; m <= 16; m <<= 1) {
            p0 += __shfl_xor(p0, m);
            p1 += __shfl_xor(p1, m);
            p2 += __shfl_xor(p2, m);
        }
        float ex0 = __expf(p0), ex1 = __expf(p1), ex2 = __expf(p2);
        if (valid) {
            if (k == 0) {
                atomicAdd(&den[(long)d * 3 + 0], ex0);
                atomicAdd(&den[(long)d * 3 + 1], ex1);
                atomicAdd(&den[(long)d * 3 + 2], ex2);
            }
            atomicAdd(&gat[(long)d * HNO + k],      ex0 * xlv0);
            atomicAdd(&gat[(long)d * HNO + k + 32], ex1 * xlv1);
            atomicAdd(&gat[(long)d * HNO + k + 64], ex2 * xlv2);
        }
        __syncthreads();
    }
}

// ---------------- K2: x_new = relu([gat/den + bias_gat, glob[batch]] @ W_n2 + b_n2) ----------------
__global__ __launch_bounds__(256) void k2_node_out(
    const float* __restrict__ gat, const float* __restrict__ den,
    const float* __restrict__ bias_gat, const float* __restrict__ glob,
    const int* __restrict__ batch, const float* __restrict__ W_n2,
    const float* __restrict__ b_n2, float* __restrict__ x_new, int niters)
{
    __shared__ float sW[128 * 32];   // 16 KB
    __shared__ float sIn[8][128];    // 4 KB
    int t = threadIdx.x;
    for (int f = t; f < 128 * 32; f += 256) sW[f] = W_n2[f];
    __syncthreads();
    int k = t & 31, ni = t >> 5;
    float bn = b_n2[k];
    for (int it = 0; it < niters; ++it) {
        long n = ((long)blockIdx.x + (long)it * gridDim.x) * 8 + ni;
        long nc = (n < N_NODES) ? n : 0;
        #pragma unroll
        for (int r = 0; r < 3; ++r) {
            int j = r * 32 + k;
            float dv = den[nc * 3 + r];
            float gv = gat[nc * HNO + j];
            sIn[ni][j] = (dv > 0.f ? gv / dv : 0.f) + bias_gat[j];
        }
        sIn[ni][96 + k] = glob[(long)batch[nc] * GI + k];
        __syncthreads();
        float acc = bn;
        #pragma unroll 8
        for (int i = 0; i < 128; ++i) acc += sIn[ni][i] * sW[i * 32 + k];
        if (n < N_NODES) x_new[n * NO + k] = fmaxf(acc, 0.f);
        __syncthreads();
    }
}

// ---------------- K3: per-graph mean of x_new (batch is sorted), then global MLP ----------------
__device__ __forceinline__ int lower_bound_dev(const int* __restrict__ a, int n, int v) {
    int lo = 0, hi = n;
    while (lo < hi) { int mid = (lo + hi) >> 1; if (a[mid] < v) lo = mid + 1; else hi = mid; }
    return lo;
}

__global__ __launch_bounds__(256) void k3_global(
    const float* __restrict__ x_new, const int* __restrict__ batch,
    const float* __restrict__ glob, const float* __restrict__ W_g,
    const float* __restrict__ b_g, float* __restrict__ u_new)
{
    __shared__ int s_lo, s_hi;
    __shared__ float s_part[8][32];
    __shared__ float s_mean[32];
    int g = blockIdx.x;
    if (threadIdx.x == 0) {
        s_lo = lower_bound_dev(batch, N_NODES, g);
        s_hi = lower_bound_dev(batch, N_NODES, g + 1);
    }
    __syncthreads();
    int lo = s_lo, hi = s_hi;
    int k = threadIdx.x & 31, c = threadIdx.x >> 5;
    float acc = 0.f;
    for (long n = lo + c; n < hi; n += 8) acc += x_new[n * NO + k];
    s_part[c][k] = acc;
    __syncthreads();
    if (threadIdx.x < 32) {
        float s = 0.f;
        #pragma unroll
        for (int c2 = 0; c2 < 8; ++c2) s += s_part[c2][k];
        int cnt = hi - lo;
        s_mean[k] = s / (float)(cnt > 0 ? cnt : 1);
    }
    __syncthreads();
    if (threadIdx.x < 32) {
        float acc2 = b_g[k];
        #pragma unroll
        for (int i = 0; i < 32; ++i) acc2 += glob[g * GI + i] * W_g[i * GO + k];
        #pragma unroll
        for (int i = 0; i < 32; ++i) acc2 += s_mean[i] * W_g[(32 + i) * GO + k];
        u_new[g * GO + k] = fmaxf(acc2, 0.f);
    }
}

extern "C" void kernel_launch(void* const* d_in, const int* in_sizes, int n_in,
                              void* d_out, int out_size, void* d_ws, size_t ws_size,
                              hipStream_t stream) {
    const float* x        = (const float*)d_in[0];
    const float* edge_attr= (const float*)d_in[1];
    const float* glob     = (const float*)d_in[2];
    const float* W_edge   = (const float*)d_in[3];
    const float* b_edge   = (const float*)d_in[4];
    const float* W_l      = (const float*)d_in[5];
    const float* b_l      = (const float*)d_in[6];
    const float* W_r      = (const float*)d_in[7];
    const float* b_r      = (const float*)d_in[8];
    const float* W_e      = (const float*)d_in[9];
    const float* att      = (const float*)d_in[10];
    const float* bias_gat = (const float*)d_in[11];
    const float* W_n2     = (const float*)d_in[12];
    const float* b_n2     = (const float*)d_in[13];
    const float* W_g      = (const float*)d_in[14];
    const float* b_g      = (const float*)d_in[15];
    const int* edge_index = (const int*)d_in[16];
    const int* batch      = (const int*)d_in[17];

    float* out   = (float*)d_out;
    float* x_new = out;                                    // N*32
    float* e_out = out + (size_t)N_NODES * NO;             // E*32
    float* u_new = e_out + (size_t)N_EDGES * EO;           // B*32

    float* ws  = (float*)d_ws;
    float* xl  = ws;                                       // N*96
    float* xr  = xl + (size_t)N_NODES * HNO;               // N*96
    float* den = xr + (size_t)N_NODES * HNO;               // N*3
    float* gat = den + (size_t)N_NODES * 3;                // N*96

    // zero den + gat (contiguous: N * (3+96) floats)
    hipMemsetAsync(den, 0, (size_t)N_NODES * 99 * sizeof(float), stream);

    int grid0 = 1024;
    int groups0 = (N_NODES + 7) / 8;                       // 12500
    int it0 = (groups0 + grid0 - 1) / grid0;
    k0_node_transform<<<grid0, 256, 0, stream>>>(x, W_l, b_l, W_r, b_r, xl, xr, it0);

    int grid1 = 2048;
    int groups1 = (N_EDGES + 7) / 8;                       // 200000
    int it1 = (groups1 + grid1 - 1) / grid1;               // 98
    k1_edge<<<grid1, 256, 0, stream>>>(x, edge_attr, W_edge, b_edge, W_e, att,
                                       edge_index, xl, xr, e_out, den, gat, it1);

    int grid2 = 1024;
    int it2 = (groups0 + grid2 - 1) / grid2;
    k2_node_out<<<grid2, 256, 0, stream>>>(gat, den, bias_gat, glob, batch,
                                           W_n2, b_n2, x_new, it2);

    k3_global<<<NB, 256, 0, stream>>>(x_new, batch, glob, W_g, b_g, u_new);
}